// Round 1
// baseline (693.626 us; speedup 1.0000x reference)
//
#include <hip/hip_runtime.h>

// Fused MHA: qkv = x@Wqkv+b ; attention ; out = attn@Wout+b
// B=4 S=2048 D=1024 H=16 hd=64. All bf16 MFMA (16x16x32), f32 accum/softmax.
//
// Workspace layout (75.5 MB):
//   [0,16.8MB)   xb (x cast to bf16)  -- reused later as attn_out (bf16)
//   [16.8,23.1)  WqkvT bf16 [3072][1024]
//   [23.1,25.2)  WoutT bf16 [1024][1024]
//   [25.2,41.9)  Qb bf16 [64 heads][2048][64]
//   [41.9,58.7)  Kb bf16 [64][2048][64]
//   [58.7,75.5)  VT bf16 [64][64][2048]   (V transposed per head)

#define S_ 2048
#define DM 1024
#define NH 16
#define HD 64

typedef unsigned short u16;
typedef unsigned int u32;
typedef __attribute__((ext_vector_type(8))) short short8;
typedef __attribute__((ext_vector_type(4))) float f32x4;

static __device__ __forceinline__ u16 f2bf(float f) {
  u32 x = __builtin_bit_cast(u32, f);
  u32 r = x + 0x7fffu + ((x >> 16) & 1u);   // RNE
  return (u16)(r >> 16);
}

#define MFMA(a, b, c) __builtin_amdgcn_mfma_f32_16x16x32_bf16((a), (b), (c), 0, 0, 0)

// ---------------- cast x (f32 -> bf16), 4 elems/thread ----------------
__global__ __launch_bounds__(256) void cast_x_kernel(const float4* __restrict__ in,
                                                     uint2* __restrict__ out, int n4) {
  int i = blockIdx.x * 256 + threadIdx.x;
  if (i >= n4) return;
  float4 v = in[i];
  uint2 o;
  o.x = (u32)f2bf(v.x) | ((u32)f2bf(v.y) << 16);
  o.y = (u32)f2bf(v.z) | ((u32)f2bf(v.w) << 16);
  out[i] = o;
}

// ------------- transpose+cast W [1024][N] f32 -> WT [N][1024] bf16 -------------
__global__ __launch_bounds__(256) void transpose_cast_kernel(const float* __restrict__ in,
                                                             u16* __restrict__ out, int N) {
  int i = blockIdx.x * 256 + threadIdx.x;          // over N*1024 outputs
  if (i >= N * 1024) return;
  int n = i >> 10, k = i & 1023;
  out[i] = f2bf(in[k * N + n]);
}

// ---------------- GEMM: C[M,N] = A[M,1024] @ BT[N,1024]^T + bias ----------------
// mode 0: scatter into Qb/Kb/VT (qkv epilogue).  mode 1: f32 out + bias.
__global__ __launch_bounds__(256) void gemm_bt_kernel(
    const u16* __restrict__ A, const u16* __restrict__ BT, const float* __restrict__ bias,
    int mode, u16* __restrict__ Qb, u16* __restrict__ Kb, u16* __restrict__ VT,
    float* __restrict__ outF) {
  __shared__ __align__(16) u16 As[128 * 32];
  __shared__ __align__(16) u16 Bs[128 * 32];
  const int tid = threadIdx.x, lane = tid & 63, wid = tid >> 6;
  const int m0 = blockIdx.y * 128, n0 = blockIdx.x * 128;
  const int wm = (wid >> 1) * 64, wn = (wid & 1) * 64;
  const int g = lane >> 4, lr = lane & 15;
  const int srow = tid >> 2, schunk = tid & 3;
  f32x4 acc[4][4] = {};

  for (int k0 = 0; k0 < 1024; k0 += 32) {
#pragma unroll
    for (int h = 0; h < 2; ++h) {
      int row = h * 64 + srow;
      int sc = schunk ^ (row & 3);   // XOR-swizzle 16B chunks
      *reinterpret_cast<short8*>(&As[row * 32 + sc * 8]) =
          *reinterpret_cast<const short8*>(&A[(m0 + row) * 1024 + k0 + schunk * 8]);
      *reinterpret_cast<short8*>(&Bs[row * 32 + sc * 8]) =
          *reinterpret_cast<const short8*>(&BT[(n0 + row) * 1024 + k0 + schunk * 8]);
    }
    __syncthreads();
    short8 af[4], bfr[4];
#pragma unroll
    for (int mb = 0; mb < 4; ++mb) {
      int row = wm + mb * 16 + lr;
      af[mb] = *reinterpret_cast<const short8*>(&As[row * 32 + (g ^ (row & 3)) * 8]);
    }
#pragma unroll
    for (int nb = 0; nb < 4; ++nb) {
      int row = wn + nb * 16 + lr;
      bfr[nb] = *reinterpret_cast<const short8*>(&Bs[row * 32 + (g ^ (row & 3)) * 8]);
    }
#pragma unroll
    for (int mb = 0; mb < 4; ++mb)
#pragma unroll
      for (int nb = 0; nb < 4; ++nb)
        acc[mb][nb] = MFMA(af[mb], bfr[nb], acc[mb][nb]);
    __syncthreads();
  }

  if (mode == 0) {
#pragma unroll
    for (int nb = 0; nb < 4; ++nb) {
      int col = n0 + wn + nb * 16 + lr;          // 0..3071
      int hh = col / 192;                        // head (small div, magic-mul)
      int c = col - hh * 192;
      int t = c >> 6, d = c & 63;
      float bv = bias[col];
#pragma unroll
      for (int mb = 0; mb < 4; ++mb)
#pragma unroll
        for (int r = 0; r < 4; ++r) {
          int rowg = m0 + wm + mb * 16 + g * 4 + r;   // token index
          int b = rowg >> 11, s = rowg & 2047;
          u16 v = f2bf(acc[mb][nb][r] + bv);
          int head = b * NH + hh;
          if (t == 0)      Qb[(head * S_ + s) * HD + d] = v;
          else if (t == 1) Kb[(head * S_ + s) * HD + d] = v;
          else             VT[(head * HD + d) * S_ + s] = v;
        }
    }
  } else {
#pragma unroll
    for (int nb = 0; nb < 4; ++nb) {
      int col = n0 + wn + nb * 16 + lr;
      float bv = bias[col];
#pragma unroll
      for (int mb = 0; mb < 4; ++mb)
#pragma unroll
        for (int r = 0; r < 4; ++r) {
          int rowg = m0 + wm + mb * 16 + g * 4 + r;
          outF[rowg * DM + col] = acc[mb][nb][r] + bv;
        }
    }
  }
}

// ---------------- flash attention, swapped-QK^T ----------------
// Per wave: 16 q-rows. Block: 4 waves = 64 q-rows. grid (32, 64 heads).
// S^T = K.Q^T (mfma: A=K rows, B=Q^T) so q-row is lane-local (col=lane&15).
// O^T = V^T.P^T accumulated; V^T layout makes A-frags contiguous.
__global__ __launch_bounds__(256) void attn_kernel(const u16* __restrict__ Qb,
                                                   const u16* __restrict__ Kb,
                                                   const u16* __restrict__ VT,
                                                   u16* __restrict__ attn_out) {
  __shared__ __align__(16) u16 plds[4][16][72];   // per-wave P^T tile, padded
  const int tid = threadIdx.x, lane = tid & 63, w = tid >> 6;
  const int head = blockIdx.y;
  const int q0 = blockIdx.x * 64 + w * 16;
  const int g = lane >> 4, lr = lane & 15;
  const u16* Qh = Qb + head * S_ * HD;
  const u16* Kh = Kb + head * S_ * HD;
  const u16* Vh = VT + head * HD * S_;

  short8 qf[2];
  qf[0] = *reinterpret_cast<const short8*>(&Qh[(q0 + lr) * HD + g * 8]);
  qf[1] = *reinterpret_cast<const short8*>(&Qh[(q0 + lr) * HD + 32 + g * 8]);

  const float scale = 0.125f;   // 1/sqrt(64)
  float m_run = -1e30f, l_run = 0.f;
  f32x4 o[4] = {};

  for (int kv0 = 0; kv0 < S_; kv0 += 64) {
    f32x4 s[4] = {};
#pragma unroll
    for (int kb = 0; kb < 2; ++kb)
#pragma unroll
      for (int mt = 0; mt < 4; ++mt) {
        short8 kf = *reinterpret_cast<const short8*>(
            &Kh[(kv0 + mt * 16 + lr) * HD + kb * 32 + g * 8]);
        s[mt] = MFMA(kf, qf[kb], s[mt]);
      }
    // online softmax (per q-row = lane&15; rows replicated over lane>>4 groups)
    float smax = -1e30f;
#pragma unroll
    for (int mt = 0; mt < 4; ++mt)
#pragma unroll
      for (int r = 0; r < 4; ++r) {
        s[mt][r] *= scale;
        smax = fmaxf(smax, s[mt][r]);
      }
    smax = fmaxf(smax, __shfl_xor(smax, 16));
    smax = fmaxf(smax, __shfl_xor(smax, 32));
    float m_new = fmaxf(m_run, smax);
    float corr = __expf(m_run - m_new);
    float psum = 0.f;
#pragma unroll
    for (int mt = 0; mt < 4; ++mt)
#pragma unroll
      for (int r = 0; r < 4; ++r) {
        float p = __expf(s[mt][r] - m_new);
        psum += p;
        plds[w][lr][mt * 16 + g * 4 + r] = f2bf(p);
      }
    psum += __shfl_xor(psum, 16);
    psum += __shfl_xor(psum, 32);
    l_run = l_run * corr + psum;
    m_run = m_new;
#pragma unroll
    for (int dt = 0; dt < 4; ++dt)
#pragma unroll
      for (int r = 0; r < 4; ++r) o[dt][r] *= corr;
    __syncthreads();   // P^T visible to all lanes (and compiler fence)
#pragma unroll
    for (int kb = 0; kb < 2; ++kb) {
      short8 pf = *reinterpret_cast<const short8*>(&plds[w][lr][kb * 32 + g * 8]);
#pragma unroll
      for (int dt = 0; dt < 4; ++dt) {
        short8 vf = *reinterpret_cast<const short8*>(
            &Vh[(dt * 16 + lr) * S_ + kv0 + kb * 32 + g * 8]);
        o[dt] = MFMA(vf, pf, o[dt]);
      }
    }
    __syncthreads();   // reads done before next iteration overwrites
  }

  const int b = head >> 4, h = head & 15;
  float inv = 1.f / l_run;
#pragma unroll
  for (int dt = 0; dt < 4; ++dt)
#pragma unroll
    for (int r = 0; r < 4; ++r) {
      int dim = dt * 16 + g * 4 + r;
      int srow = q0 + lr;
      attn_out[(b * S_ + srow) * DM + h * HD + dim] = f2bf(o[dt][r] * inv);
    }
}

extern "C" void kernel_launch(void* const* d_in, const int* in_sizes, int n_in,
                              void* d_out, int out_size, void* d_ws, size_t ws_size,
                              hipStream_t stream) {
  const float* x    = (const float*)d_in[0];
  const float* Wqkv = (const float*)d_in[1];
  const float* bqkv = (const float*)d_in[2];
  const float* Wout = (const float*)d_in[3];
  const float* bout = (const float*)d_in[4];
  float* out = (float*)d_out;

  char* ws = (char*)d_ws;
  u16* xb      = (u16*)(ws);                  // 8192*1024
  u16* WqkvT   = (u16*)(ws + 16777216);       // 3072*1024
  u16* WoutT   = (u16*)(ws + 23068672);       // 1024*1024
  u16* Qb      = (u16*)(ws + 25165824);       // 64*2048*64
  u16* Kb      = (u16*)(ws + 41943040);
  u16* VT      = (u16*)(ws + 58720256);
  u16* attn_out = xb;                          // reuse after gemm1 consumed x

  // prep
  cast_x_kernel<<<8192, 256, 0, stream>>>((const float4*)x, (uint2*)xb, 8192 * 1024 / 4);
  transpose_cast_kernel<<<12288, 256, 0, stream>>>(Wqkv, WqkvT, 3072);
  transpose_cast_kernel<<<4096, 256, 0, stream>>>(Wout, WoutT, 1024);

  // qkv = x @ Wqkv + bqkv  (scatter to Q/K/V^T per head)
  gemm_bt_kernel<<<dim3(24, 64), 256, 0, stream>>>(xb, WqkvT, bqkv, 0, Qb, Kb, VT, nullptr);

  // attention
  attn_kernel<<<dim3(32, 64), 256, 0, stream>>>(Qb, Kb, VT, attn_out);

  // out = attn @ Wout + bout
  gemm_bt_kernel<<<dim3(8, 64), 256, 0, stream>>>(attn_out, WoutT, bout, 1, nullptr, nullptr,
                                                  nullptr, out);
}

// Round 2
// 669.538 us; speedup vs baseline: 1.0360x; 1.0360x over previous
//
#include <hip/hip_runtime.h>
#include <hip/hip_bf16.h>

// Fused MHA: qkv = x@Wqkv+b ; attention ; out = attn@Wout+b
// B=4 S=2048 D=1024 H=16 hd=64. bf16 MFMA 16x16x32, f32 accum/softmax.

#define S_ 2048
#define DM 1024
#define NH 16
#define HD 64

typedef unsigned short u16;
typedef unsigned int u32;
typedef __attribute__((ext_vector_type(8))) short short8;
typedef __attribute__((ext_vector_type(4))) float f32x4;

extern "C" __device__ float __ocml_native_exp2_f32(float);

#define MFMA(a, b, c) __builtin_amdgcn_mfma_f32_16x16x32_bf16((a), (b), (c), 0, 0, 0)

static __device__ __forceinline__ u16 f2bf(float f) {
  return __builtin_bit_cast(u16, __float2bfloat16(f));
}
static __device__ __forceinline__ u32 pack2bf(float a, float b) {
  return (u32)f2bf(a) | ((u32)f2bf(b) << 16);
}
// async global->LDS, 16B per lane; lds base must be wave-uniform (lane*16 auto)
static __device__ __forceinline__ void gl_lds16(const u16* g, u16* l) {
  __builtin_amdgcn_global_load_lds((__attribute__((address_space(1))) void*)(u16*)g,
                                   (__attribute__((address_space(3))) void*)l, 16, 0, 0);
}

// ---------------- cast x (f32 -> bf16) ----------------
__global__ __launch_bounds__(256) void cast_x_kernel(const float4* __restrict__ in,
                                                     uint2* __restrict__ out, int n4) {
  int i = blockIdx.x * 256 + threadIdx.x;
  if (i >= n4) return;
  float4 v = in[i];
  uint2 o;
  o.x = pack2bf(v.x, v.y);
  o.y = pack2bf(v.z, v.w);
  out[i] = o;
}

// ---- tiled transpose+cast: in [1024][N] f32 -> out [N][1024] bf16 ----
__global__ __launch_bounds__(256) void transpose_cast_kernel(const float* __restrict__ in,
                                                             u16* __restrict__ out, int N) {
  __shared__ float tile[32][33];
  const int bk = blockIdx.y * 32, bn = blockIdx.x * 32;
  const int r = threadIdx.x >> 3, c4 = (threadIdx.x & 7) * 4;
  float4 v = *reinterpret_cast<const float4*>(&in[(size_t)(bk + r) * N + bn + c4]);
  tile[r][c4 + 0] = v.x; tile[r][c4 + 1] = v.y;
  tile[r][c4 + 2] = v.z; tile[r][c4 + 3] = v.w;
  __syncthreads();
  uint2 o;
  o.x = pack2bf(tile[c4 + 0][r], tile[c4 + 1][r]);
  o.y = pack2bf(tile[c4 + 2][r], tile[c4 + 3][r]);
  *reinterpret_cast<uint2*>(&out[(size_t)(bn + r) * 1024 + bk + c4]) = o;
}

// ---------------- GEMM: C[M,N] = A[M,1024] @ BT[N,1024]^T + bias ----------------
__global__ __launch_bounds__(256) void gemm_bt_kernel(
    const u16* __restrict__ A, const u16* __restrict__ BT, const float* __restrict__ bias,
    int mode, u16* __restrict__ Qb, u16* __restrict__ Kb, u16* __restrict__ VT,
    float* __restrict__ outF) {
  __shared__ __align__(16) u16 As[128 * 32];
  __shared__ __align__(16) u16 Bs[128 * 32];
  const int tid = threadIdx.x, lane = tid & 63, wid = tid >> 6;
  const int m0 = blockIdx.y * 128, n0 = blockIdx.x * 128;
  const int wm = (wid >> 1) * 64, wn = (wid & 1) * 64;
  const int g = lane >> 4, lr = lane & 15;
  const int srow16 = lane >> 2, scol8 = (lane & 3) * 8;
  f32x4 acc[4][4] = {};

  for (int k0 = 0; k0 < 1024; k0 += 32) {
#pragma unroll
    for (int i = 0; i < 2; ++i) {
      int sA = wid + i * 4;                       // 8 segments of 16 rows each
      gl_lds16(&A[(size_t)(m0 + sA * 16 + srow16) * 1024 + k0 + scol8], &As[sA * 512]);
      gl_lds16(&BT[(size_t)(n0 + sA * 16 + srow16) * 1024 + k0 + scol8], &Bs[sA * 512]);
    }
    __syncthreads();                               // drains vmcnt
    short8 af[4], bfr[4];
#pragma unroll
    for (int mb = 0; mb < 4; ++mb)
      af[mb] = *reinterpret_cast<const short8*>(&As[(wm + mb * 16 + lr) * 32 + g * 8]);
#pragma unroll
    for (int nb = 0; nb < 4; ++nb)
      bfr[nb] = *reinterpret_cast<const short8*>(&Bs[(wn + nb * 16 + lr) * 32 + g * 8]);
#pragma unroll
    for (int mb = 0; mb < 4; ++mb)
#pragma unroll
      for (int nb = 0; nb < 4; ++nb)
        acc[mb][nb] = MFMA(af[mb], bfr[nb], acc[mb][nb]);
    __syncthreads();
  }

  if (mode == 0) {
#pragma unroll
    for (int nb = 0; nb < 4; ++nb) {
      int col = n0 + wn + nb * 16 + lr;          // 0..3071
      int hh = col / 192;
      int c = col - hh * 192;
      int t = c >> 6, d = c & 63;
      float bv = bias[col];
#pragma unroll
      for (int mb = 0; mb < 4; ++mb)
#pragma unroll
        for (int r = 0; r < 4; ++r) {
          int rowg = m0 + wm + mb * 16 + g * 4 + r;
          int b = rowg >> 11, s = rowg & 2047;
          u16 v = f2bf(acc[mb][nb][r] + bv);
          int head = b * NH + hh;
          if (t == 0)      Qb[(head * S_ + s) * HD + d] = v;
          else if (t == 1) Kb[(head * S_ + s) * HD + d] = v;
          else             VT[((size_t)head * HD + d) * S_ + s] = v;
        }
    }
  } else {
#pragma unroll
    for (int nb = 0; nb < 4; ++nb) {
      int col = n0 + wn + nb * 16 + lr;
      float bv = bias[col];
#pragma unroll
      for (int mb = 0; mb < 4; ++mb)
#pragma unroll
        for (int r = 0; r < 4; ++r) {
          int rowg = m0 + wm + mb * 16 + g * 4 + r;
          outF[(size_t)rowg * DM + col] = acc[mb][nb][r] + bv;
        }
    }
  }
}

// ---------------- flash attention, swapped-QK^T, per-wave P-tile ----------------
// No block barriers: plds row is shared only among the 4 g-group lanes of a wave.
#define C1 0.18033688f   // 0.125 * log2(e)

static __device__ __forceinline__ void attn_step(
    int kv0, const u16* __restrict__ Kh, const u16* __restrict__ Vh,
    short8 (&kcur)[8], short8 (&knxt)[8], const short8 (&qf)[2],
    float& m_run, float& l_run, f32x4 (&o)[4], u32* __restrict__ prow,
    int g, int lr) {
  const int t = lr & 7;
  const int kvn = (kv0 + 64) & (S_ - 1);
  // V loads for this tile (latency hidden under QK^T + softmax)
  short8 vf[8];
#pragma unroll
  for (int dt = 0; dt < 4; ++dt)
#pragma unroll
    for (int kb = 0; kb < 2; ++kb)
      vf[dt * 2 + kb] = *reinterpret_cast<const short8*>(
          &Vh[(dt * 16 + lr) * S_ + kv0 + kb * 32 + g * 8]);
  // S^T = K . Q^T  (s[mt][r]: k = kv0+mt*16+g*4+r, q = lr)
  f32x4 s[4] = {};
#pragma unroll
  for (int kb = 0; kb < 2; ++kb)
#pragma unroll
    for (int mt = 0; mt < 4; ++mt)
      s[mt] = MFMA(kcur[kb * 4 + mt], qf[kb], s[mt]);
  // prefetch next K tile (hidden under softmax + PV)
#pragma unroll
  for (int kb = 0; kb < 2; ++kb)
#pragma unroll
    for (int mt = 0; mt < 4; ++mt)
      knxt[kb * 4 + mt] = *reinterpret_cast<const short8*>(
          &Kh[(kvn + mt * 16 + lr) * HD + kb * 32 + g * 8]);
  // online softmax in raw-score space; exp2 with folded scale
  float smax = -3e38f;
#pragma unroll
  for (int mt = 0; mt < 4; ++mt)
#pragma unroll
    for (int r = 0; r < 4; ++r) smax = fmaxf(smax, s[mt][r]);
  smax = fmaxf(smax, __shfl_xor(smax, 16));
  smax = fmaxf(smax, __shfl_xor(smax, 32));
  bool keep = __all(smax <= m_run + 40.0f);       // T13 defer-max (p <= 2^7.2)
  float m_new = keep ? m_run : fmaxf(m_run, smax);
  float base = m_new * C1;
  float psum = 0.f;
#pragma unroll
  for (int mt = 0; mt < 4; ++mt)
#pragma unroll
    for (int r = 0; r < 4; ++r) {
      float p = __ocml_native_exp2_f32(fmaf(s[mt][r], C1, -base));
      s[mt][r] = p;
      psum += p;
    }
  psum += __shfl_xor(psum, 16);
  psum += __shfl_xor(psum, 32);
  if (keep) {
    l_run += psum;
  } else {
    float corr = __ocml_native_exp2_f32((m_run - m_new) * C1);
    l_run = l_run * corr + psum;
    m_run = m_new;
#pragma unroll
    for (int dt = 0; dt < 4; ++dt)
#pragma unroll
      for (int r = 0; r < 4; ++r) o[dt][r] *= corr;
  }
  // pack P pairs -> own row (swizzled 16B chunks), cross-g exchange via LDS
#pragma unroll
  for (int mt = 0; mt < 4; ++mt)
#pragma unroll
    for (int r01 = 0; r01 < 2; ++r01) {
      u32 pk = pack2bf(s[mt][r01 * 2], s[mt][r01 * 2 + 1]);
      int cc = (mt * 2 + (g >> 1)) ^ t;
      prow[cc * 4 + (g & 1) * 2 + r01] = pk;
    }
  asm volatile("s_waitcnt lgkmcnt(0)" ::: "memory");
  // O^T += V^T . P^T
#pragma unroll
  for (int kb = 0; kb < 2; ++kb) {
    short8 pf = *reinterpret_cast<const short8*>(&prow[((kb * 4 + g) ^ t) * 4]);
#pragma unroll
    for (int dt = 0; dt < 4; ++dt)
      o[dt] = MFMA(vf[dt * 2 + kb], pf, o[dt]);
  }
}

__global__ __launch_bounds__(256) void attn_kernel(const u16* __restrict__ Qb,
                                                   const u16* __restrict__ Kb,
                                                   const u16* __restrict__ VT,
                                                   u16* __restrict__ attn_out) {
  __shared__ __align__(16) u32 plds[4][16][40];   // 160B row stride
  const int tid = threadIdx.x, lane = tid & 63, w = tid >> 6;
  const int head = blockIdx.y;
  const int q0 = blockIdx.x * 64 + w * 16;
  const int g = lane >> 4, lr = lane & 15;
  const u16* Qh = Qb + (size_t)head * S_ * HD;
  const u16* Kh = Kb + (size_t)head * S_ * HD;
  const u16* Vh = VT + (size_t)head * HD * S_;
  u32* prow = &plds[w][lr][0];

  short8 qf[2];
  qf[0] = *reinterpret_cast<const short8*>(&Qh[(q0 + lr) * HD + g * 8]);
  qf[1] = *reinterpret_cast<const short8*>(&Qh[(q0 + lr) * HD + 32 + g * 8]);

  float m_run = -1e30f, l_run = 0.f;
  f32x4 o[4] = {};
  short8 kA[8], kB[8];
#pragma unroll
  for (int kb = 0; kb < 2; ++kb)
#pragma unroll
    for (int mt = 0; mt < 4; ++mt)
      kA[kb * 4 + mt] = *reinterpret_cast<const short8*>(
          &Kh[(mt * 16 + lr) * HD + kb * 32 + g * 8]);

#pragma unroll 1
  for (int kv0 = 0; kv0 < S_; kv0 += 128) {
    attn_step(kv0,      Kh, Vh, kA, kB, qf, m_run, l_run, o, prow, g, lr);
    attn_step(kv0 + 64, Kh, Vh, kB, kA, qf, m_run, l_run, o, prow, g, lr);
  }

  const int b = head >> 4, h = head & 15;
  float inv = 1.f / l_run;
  u16* dst = attn_out + (size_t)(b * S_ + q0 + lr) * DM + h * HD;
#pragma unroll
  for (int dt = 0; dt < 4; ++dt) {
    uint2 pk;
    pk.x = pack2bf(o[dt][0] * inv, o[dt][1] * inv);
    pk.y = pack2bf(o[dt][2] * inv, o[dt][3] * inv);
    *reinterpret_cast<uint2*>(dst + dt * 16 + g * 4) = pk;
  }
}

extern "C" void kernel_launch(void* const* d_in, const int* in_sizes, int n_in,
                              void* d_out, int out_size, void* d_ws, size_t ws_size,
                              hipStream_t stream) {
  const float* x    = (const float*)d_in[0];
  const float* Wqkv = (const float*)d_in[1];
  const float* bqkv = (const float*)d_in[2];
  const float* Wout = (const float*)d_in[3];
  const float* bout = (const float*)d_in[4];
  float* out = (float*)d_out;

  char* ws = (char*)d_ws;
  u16* xb      = (u16*)(ws);                  // 8192*1024 bf16
  u16* WqkvT   = (u16*)(ws + 16777216);       // 3072*1024
  u16* WoutT   = (u16*)(ws + 23068672);       // 1024*1024
  u16* Qb      = (u16*)(ws + 25165824);       // 64*2048*64
  u16* Kb      = (u16*)(ws + 41943040);
  u16* VT      = (u16*)(ws + 58720256);
  u16* attn_out = xb;                          // reuse after gemm1 consumed x

  cast_x_kernel<<<8192, 256, 0, stream>>>((const float4*)x, (uint2*)xb, 8192 * 1024 / 4);
  transpose_cast_kernel<<<dim3(96, 32), 256, 0, stream>>>(Wqkv, WqkvT, 3072);
  transpose_cast_kernel<<<dim3(32, 32), 256, 0, stream>>>(Wout, WoutT, 1024);

  gemm_bt_kernel<<<dim3(24, 64), 256, 0, stream>>>(xb, WqkvT, bqkv, 0, Qb, Kb, VT, nullptr);
  attn_kernel<<<dim3(32, 64), 256, 0, stream>>>(Qb, Kb, VT, attn_out);
  gemm_bt_kernel<<<dim3(8, 64), 256, 0, stream>>>(attn_out, WoutT, bout, 1, nullptr, nullptr,
                                                  nullptr, out);
}

// Round 4
// 450.074 us; speedup vs baseline: 1.5411x; 1.4876x over previous
//
#include <hip/hip_runtime.h>
#include <hip/hip_bf16.h>

// Fused MHA: qkv = x@Wqkv+b ; attention ; out = attn@Wout+b
// B=4 S=2048 D=1024 H=16 hd=64. bf16 MFMA, f32 accum/softmax.
// attn: 32x32x16 MFMA, LDS-free softmax/PV via lane<->lane+32 exchange.

#define S_ 2048
#define DM 1024
#define NH 16
#define HD 64

typedef unsigned short u16;
typedef unsigned int u32;
typedef __attribute__((ext_vector_type(8))) short short8;
typedef __attribute__((ext_vector_type(4))) float f32x4;
typedef __attribute__((ext_vector_type(16))) float f32x16;
typedef __attribute__((ext_vector_type(4))) u32 u32x4;

extern "C" __device__ float __ocml_native_exp2_f32(float);

#define MFMA(a, b, c) __builtin_amdgcn_mfma_f32_16x16x32_bf16((a), (b), (c), 0, 0, 0)
#define MFMA32(a, b, c) __builtin_amdgcn_mfma_f32_32x32x16_bf16((a), (b), (c), 0, 0, 0)
#define C1 0.18033688f   // 0.125 * log2(e)

static __device__ __forceinline__ u16 f2bf(float f) {
  return __builtin_bit_cast(u16, __float2bfloat16(f));
}
static __device__ __forceinline__ u32 pack2bf(float a, float b) {
  return (u32)f2bf(a) | ((u32)f2bf(b) << 16);
}
static __device__ __forceinline__ short8 ld8(const u16* p) {
  return *reinterpret_cast<const short8*>(p);
}
static __device__ __forceinline__ void gl_lds16(const u16* g, u16* l) {
  __builtin_amdgcn_global_load_lds((__attribute__((address_space(1))) void*)(u16*)g,
                                   (__attribute__((address_space(3))) void*)l, 16, 0, 0);
}

// ---------------- cast x (f32 -> bf16) ----------------
__global__ __launch_bounds__(256) void cast_x_kernel(const float4* __restrict__ in,
                                                     uint2* __restrict__ out, int n4) {
  int i = blockIdx.x * 256 + threadIdx.x;
  if (i >= n4) return;
  float4 v = in[i];
  uint2 o;
  o.x = pack2bf(v.x, v.y);
  o.y = pack2bf(v.z, v.w);
  out[i] = o;
}

// ---- tiled transpose+cast: in [1024][N] f32 -> out [N][1024] bf16 ----
__global__ __launch_bounds__(256) void transpose_cast_kernel(const float* __restrict__ in,
                                                             u16* __restrict__ out, int N) {
  __shared__ float tile[32][33];
  const int bk = blockIdx.y * 32, bn = blockIdx.x * 32;
  const int r = threadIdx.x >> 3, c4 = (threadIdx.x & 7) * 4;
  float4 v = *reinterpret_cast<const float4*>(&in[(size_t)(bk + r) * N + bn + c4]);
  tile[r][c4 + 0] = v.x; tile[r][c4 + 1] = v.y;
  tile[r][c4 + 2] = v.z; tile[r][c4 + 3] = v.w;
  __syncthreads();
  uint2 o;
  o.x = pack2bf(tile[c4 + 0][r], tile[c4 + 1][r]);
  o.y = pack2bf(tile[c4 + 2][r], tile[c4 + 3][r]);
  *reinterpret_cast<uint2*>(&out[(size_t)(bn + r) * 1024 + bk + c4]) = o;
}

// ---------------- GEMM: C[M,N] = A[M,1024] @ BT[N,1024]^T + bias ----------------
__global__ __launch_bounds__(256) void gemm_bt_kernel(
    const u16* __restrict__ A, const u16* __restrict__ BT, const float* __restrict__ bias,
    int mode, u16* __restrict__ Qb, u16* __restrict__ Kb, u16* __restrict__ VT,
    float* __restrict__ outF) {
  __shared__ __align__(16) u16 As[128 * 32];
  __shared__ __align__(16) u16 Bs[128 * 32];
  const int tid = threadIdx.x, lane = tid & 63, wid = tid >> 6;
  const int m0 = blockIdx.y * 128, n0 = blockIdx.x * 128;
  const int wm = (wid >> 1) * 64, wn = (wid & 1) * 64;
  const int g = lane >> 4, lr = lane & 15;
  const int srow16 = lane >> 2, scol8 = (lane & 3) * 8;
  f32x4 acc[4][4] = {};

  for (int k0 = 0; k0 < 1024; k0 += 32) {
#pragma unroll
    for (int i = 0; i < 2; ++i) {
      int sA = wid + i * 4;
      gl_lds16(&A[(size_t)(m0 + sA * 16 + srow16) * 1024 + k0 + scol8], &As[sA * 512]);
      gl_lds16(&BT[(size_t)(n0 + sA * 16 + srow16) * 1024 + k0 + scol8], &Bs[sA * 512]);
    }
    __syncthreads();
    short8 af[4], bfr[4];
#pragma unroll
    for (int mb = 0; mb < 4; ++mb)
      af[mb] = ld8(&As[(wm + mb * 16 + lr) * 32 + g * 8]);
#pragma unroll
    for (int nb = 0; nb < 4; ++nb)
      bfr[nb] = ld8(&Bs[(wn + nb * 16 + lr) * 32 + g * 8]);
#pragma unroll
    for (int mb = 0; mb < 4; ++mb)
#pragma unroll
      for (int nb = 0; nb < 4; ++nb)
        acc[mb][nb] = MFMA(af[mb], bfr[nb], acc[mb][nb]);
    __syncthreads();
  }

  if (mode == 0) {
#pragma unroll
    for (int nb = 0; nb < 4; ++nb) {
      int col = n0 + wn + nb * 16 + lr;          // 0..3071
      int hh = col / 192;
      int c = col - hh * 192;
      int t = c >> 6, d = c & 63;
      float bv = bias[col];
#pragma unroll
      for (int mb = 0; mb < 4; ++mb)
#pragma unroll
        for (int r = 0; r < 4; ++r) {
          int rowg = m0 + wm + mb * 16 + g * 4 + r;
          int b = rowg >> 11, s = rowg & 2047;
          u16 v = f2bf(acc[mb][nb][r] + bv);
          int head = b * NH + hh;
          if (t == 0)      Qb[(head * S_ + s) * HD + d] = v;
          else if (t == 1) Kb[(head * S_ + s) * HD + d] = v;
          else             VT[((size_t)head * HD + d) * S_ + s] = v;
        }
    }
  } else {
#pragma unroll
    for (int nb = 0; nb < 4; ++nb) {
      int col = n0 + wn + nb * 16 + lr;
      float bv = bias[col];
#pragma unroll
      for (int mb = 0; mb < 4; ++mb)
#pragma unroll
        for (int r = 0; r < 4; ++r) {
          int rowg = m0 + wm + mb * 16 + g * 4 + r;
          outF[(size_t)rowg * DM + col] = acc[mb][nb][r] + bv;
        }
    }
  }
}

// ---------------- flash attention, 32x32x16, LDS-free ----------------
// Wave: 32 q-rows. S^T = K.Q^T -> lane holds 32 scores of ONE q (col=lane&31).
// C-layout: row k_local = (r&3)+8*(r>>2)+4*hi. P redistribution for PV via
// lane<->lane^32 shfl of packed bf16 pairs. No LDS, no barriers.
__global__ __launch_bounds__(256, 2) void attn_kernel(const u16* __restrict__ Qb,
                                                      const u16* __restrict__ Kb,
                                                      const u16* __restrict__ VT,
                                                      u16* __restrict__ attn_out) {
  const int lane = threadIdx.x & 63, wid = threadIdx.x >> 6;
  const int head = blockIdx.y;
  const int l31 = lane & 31, hi = lane >> 5;
  const int q = blockIdx.x * 128 + wid * 32 + l31;
  const u16* Qh = Qb + (size_t)head * S_ * HD;
  const u16* Kh = Kb + (size_t)head * S_ * HD;
  const u16* Vh = VT + (size_t)head * HD * S_;

  short8 qf[4];
#pragma unroll
  for (int dt = 0; dt < 4; ++dt)
    qf[dt] = ld8(&Qh[q * HD + dt * 16 + hi * 8]);

  short8 kf[2][4];
#pragma unroll
  for (int kt = 0; kt < 2; ++kt)
#pragma unroll
    for (int dt = 0; dt < 4; ++dt)
      kf[kt][dt] = ld8(&Kh[(kt * 32 + l31) * HD + dt * 16 + hi * 8]);

  f32x16 o0 = {}, o1 = {};
  float m_run = -1e30f, l_run = 0.f;

#pragma unroll 1
  for (int kv0 = 0; kv0 < S_; kv0 += 64) {
    // V loads for this tile (consumed after softmax)
    short8 vf0[4], vf1[4];
#pragma unroll
    for (int kc = 0; kc < 4; ++kc) {
      vf0[kc] = ld8(&Vh[(size_t)l31 * S_ + kv0 + kc * 16 + hi * 8]);
      vf1[kc] = ld8(&Vh[(size_t)(32 + l31) * S_ + kv0 + kc * 16 + hi * 8]);
    }
    // S^T = K . Q^T
    f32x16 s0 = {}, s1 = {};
#pragma unroll
    for (int dt = 0; dt < 4; ++dt) s0 = MFMA32(kf[0][dt], qf[dt], s0);
#pragma unroll
    for (int dt = 0; dt < 4; ++dt) s1 = MFMA32(kf[1][dt], qf[dt], s1);
    // prefetch next K tile (consumed next iteration)
    int kvn = (kv0 + 64) & (S_ - 1);
#pragma unroll
    for (int kt = 0; kt < 2; ++kt)
#pragma unroll
      for (int dt = 0; dt < 4; ++dt)
        kf[kt][dt] = ld8(&Kh[(kvn + kt * 32 + l31) * HD + dt * 16 + hi * 8]);
    // row max: in-lane tree over 32 + one cross-half exchange
    float mx[8];
#pragma unroll
    for (int r = 0; r < 8; ++r)
      mx[r] = fmaxf(fmaxf(s0[r], s0[r + 8]), fmaxf(s1[r], s1[r + 8]));
    float m01 = fmaxf(fmaxf(mx[0], mx[1]), fmaxf(mx[2], mx[3]));
    float m23 = fmaxf(fmaxf(mx[4], mx[5]), fmaxf(mx[6], mx[7]));
    float smax = fmaxf(m01, m23);
    smax = fmaxf(smax, __shfl_xor(smax, 32));
    bool keep = __all(smax <= m_run + 40.0f);     // T13 defer-max
    float m_new = keep ? m_run : fmaxf(m_run, smax);
    float base = m_new * C1;
    float p0 = 0.f, p1 = 0.f, p2 = 0.f, p3 = 0.f;
#pragma unroll
    for (int m = 0; m < 4; ++m) {
      s0[m * 4 + 0] = __ocml_native_exp2_f32(fmaf(s0[m * 4 + 0], C1, -base));
      s0[m * 4 + 1] = __ocml_native_exp2_f32(fmaf(s0[m * 4 + 1], C1, -base));
      s0[m * 4 + 2] = __ocml_native_exp2_f32(fmaf(s0[m * 4 + 2], C1, -base));
      s0[m * 4 + 3] = __ocml_native_exp2_f32(fmaf(s0[m * 4 + 3], C1, -base));
      s1[m * 4 + 0] = __ocml_native_exp2_f32(fmaf(s1[m * 4 + 0], C1, -base));
      s1[m * 4 + 1] = __ocml_native_exp2_f32(fmaf(s1[m * 4 + 1], C1, -base));
      s1[m * 4 + 2] = __ocml_native_exp2_f32(fmaf(s1[m * 4 + 2], C1, -base));
      s1[m * 4 + 3] = __ocml_native_exp2_f32(fmaf(s1[m * 4 + 3], C1, -base));
      p0 += s0[m * 4 + 0] + s1[m * 4 + 0];
      p1 += s0[m * 4 + 1] + s1[m * 4 + 1];
      p2 += s0[m * 4 + 2] + s1[m * 4 + 2];
      p3 += s0[m * 4 + 3] + s1[m * 4 + 3];
    }
    float psum = (p0 + p1) + (p2 + p3);
    psum += __shfl_xor(psum, 32);
    if (keep) {
      l_run += psum;
    } else {
      float corr = __ocml_native_exp2_f32((m_run - m_new) * C1);
      l_run = l_run * corr + psum;
      m_run = m_new;
#pragma unroll
      for (int r = 0; r < 16; ++r) { o0[r] *= corr; o1[r] *= corr; }
    }
    // pack P pairs: octet O=kt*4+m holds k = kt*32+8m+4hi+{0..3}
    u32 wA[8], wB[8];
#pragma unroll
    for (int m = 0; m < 4; ++m) {
      wA[m] = pack2bf(s0[m * 4 + 0], s0[m * 4 + 1]);
      wB[m] = pack2bf(s0[m * 4 + 2], s0[m * 4 + 3]);
      wA[4 + m] = pack2bf(s1[m * 4 + 0], s1[m * 4 + 1]);
      wB[4 + m] = pack2bf(s1[m * 4 + 2], s1[m * 4 + 3]);
    }
    // PV: per 16-k chunk kc, assemble B-frag (k = kc*16+8hi+j) via one exchange
#pragma unroll
    for (int kc = 0; kc < 4; ++kc) {
      u32 sendA = hi ? wA[2 * kc] : wA[2 * kc + 1];
      u32 sendB = hi ? wB[2 * kc] : wB[2 * kc + 1];
      u32 recvA = (u32)__shfl_xor((int)sendA, 32);
      u32 recvB = (u32)__shfl_xor((int)sendB, 32);
      u32x4 bw;
      bw.x = hi ? recvA : wA[2 * kc];
      bw.y = hi ? recvB : wB[2 * kc];
      bw.z = hi ? wA[2 * kc + 1] : recvA;
      bw.w = hi ? wB[2 * kc + 1] : recvB;
      short8 pf = __builtin_bit_cast(short8, bw);
      o0 = MFMA32(vf0[kc], pf, o0);
      o1 = MFMA32(vf1[kc], pf, o1);
    }
  }

  const int b = head >> 4, h = head & 15;
  float inv = 1.f / l_run;
  u16* dst = attn_out + (size_t)(b * S_ + q) * DM + h * HD;
#pragma unroll
  for (int rg = 0; rg < 4; ++rg) {
    uint2 k0, k1;
    k0.x = pack2bf(o0[rg * 4 + 0] * inv, o0[rg * 4 + 1] * inv);
    k0.y = pack2bf(o0[rg * 4 + 2] * inv, o0[rg * 4 + 3] * inv);
    *reinterpret_cast<uint2*>(dst + rg * 8 + hi * 4) = k0;
    k1.x = pack2bf(o1[rg * 4 + 0] * inv, o1[rg * 4 + 1] * inv);
    k1.y = pack2bf(o1[rg * 4 + 2] * inv, o1[rg * 4 + 3] * inv);
    *reinterpret_cast<uint2*>(dst + 32 + rg * 8 + hi * 4) = k1;
  }
}

extern "C" void kernel_launch(void* const* d_in, const int* in_sizes, int n_in,
                              void* d_out, int out_size, void* d_ws, size_t ws_size,
                              hipStream_t stream) {
  const float* x    = (const float*)d_in[0];
  const float* Wqkv = (const float*)d_in[1];
  const float* bqkv = (const float*)d_in[2];
  const float* Wout = (const float*)d_in[3];
  const float* bout = (const float*)d_in[4];
  float* out = (float*)d_out;

  char* ws = (char*)d_ws;
  u16* xb      = (u16*)(ws);                  // 8192*1024 bf16
  u16* WqkvT   = (u16*)(ws + 16777216);       // 3072*1024
  u16* WoutT   = (u16*)(ws + 23068672);       // 1024*1024
  u16* Qb      = (u16*)(ws + 25165824);       // 64*2048*64
  u16* Kb      = (u16*)(ws + 41943040);
  u16* VT      = (u16*)(ws + 58720256);
  u16* attn_out = xb;                          // reuse after gemm1 consumed x

  cast_x_kernel<<<8192, 256, 0, stream>>>((const float4*)x, (uint2*)xb, 8192 * 1024 / 4);
  transpose_cast_kernel<<<dim3(96, 32), 256, 0, stream>>>(Wqkv, WqkvT, 3072);
  transpose_cast_kernel<<<dim3(32, 32), 256, 0, stream>>>(Wout, WoutT, 1024);

  gemm_bt_kernel<<<dim3(24, 64), 256, 0, stream>>>(xb, WqkvT, bqkv, 0, Qb, Kb, VT, nullptr);
  attn_kernel<<<dim3(16, 64), 256, 0, stream>>>(Qb, Kb, VT, attn_out);
  gemm_bt_kernel<<<dim3(8, 64), 256, 0, stream>>>(attn_out, WoutT, bout, 1, nullptr, nullptr,
                                                  nullptr, out);
}